// Round 2
// baseline (717.390 us; speedup 1.0000x reference)
//
#include <hip/hip_runtime.h>

#define T_STEPS 1024
#define LOG2E 1.44269504088896340736f
// H = F = 6; 24 gate rows in PyTorch order: i[0:6) f[6:12) g[12:18) o[18:24)
// Mapping: 32 lanes per batch element (2 elements per wave64).
//   half-lane hl = lane&31; gate row r = hl (hl<24), lanes 24..31 are ballast.
//   => 4096 elem * 32 lanes = 131072 threads = 2048 waves = 2 waves/SIMD.

__device__ __forceinline__ float vexp2(float x) { return __builtin_amdgcn_exp2f(x); }
__device__ __forceinline__ float vrcp(float x)  { return __builtin_amdgcn_rcpf(x); }
__device__ __forceinline__ float bperm(int a4, float v) {
    return __int_as_float(__builtin_amdgcn_ds_bpermute(a4, __float_as_int(v)));
}

__global__ __launch_bounds__(256) void lstm2_kernel(
    const float* __restrict__ x,
    const float* __restrict__ wih0, const float* __restrict__ whh0,
    const float* __restrict__ bih0, const float* __restrict__ bhh0,
    const float* __restrict__ wih1, const float* __restrict__ whh1,
    const float* __restrict__ bih1, const float* __restrict__ bhh1,
    float* __restrict__ out, int Btot)
{
    const int tid  = threadIdx.x;
    const int lane = tid & 63;
    const int hl   = lane & 31;        // lane within element
    const int eb   = lane & 32;        // element's base lane within the wave
    int r = hl; if (r >= 24) r -= 24;  // gate row (lanes 24..31 duplicate rows 0..7, unused)

    int b = blockIdx.x * 8 + (tid >> 5);     // 8 elements per 256-thread block
    const bool valid = (b < Btot);
    if (!valid) b = Btot - 1;                // clamp; stores predicated off

    // per-row activation constants: sigma(x)=rcp(1+exp2(-x*log2e));
    // tanh(x)=2*sigma(2x)-1 -> fold the 2x into the exponent scale.
    const int ph = r / 6;                    // 0:i 1:f 2:g 3:o
    const float kscale = (ph == 2) ? (-2.0f * LOG2E) : (-LOG2E);
    const float mulc   = (ph == 2) ? 2.0f : 1.0f;
    const float addc   = (ph == 2) ? -1.0f : 0.0f;

    // row weights (L1-broadcast scalarish loads, once)
    float wih0v[6], whh0v[6], wih1v[6], whh1v[6];
#pragma unroll
    for (int k = 0; k < 6; ++k) {
        wih0v[k] = wih0[r * 6 + k]; whh0v[k] = whh0[r * 6 + k];
        wih1v[k] = wih1[r * 6 + k]; whh1v[k] = whh1[r * 6 + k];
    }
    const float b0 = bih0[r] + bhh0[r];
    const float b1 = bih1[r] + bhh1[r];

    // bpermute byte-addresses (precomputed, loop-invariant)
    const int jj  = (hl < 6) ? hl : 0;       // only hl<6 lanes' gathers are used
    const int giF = (eb + jj + 6)  * 4;      // sigma(f_j) lives on lane eb+j+6
    const int giG = (eb + jj + 12) * 4;      // tanh(g_j)
    const int giO = (eb + jj + 18) * 4;      // sigma(o_j)
    int biX[6];
#pragma unroll
    for (int k = 0; k < 6; ++k) biX[k] = (eb + k) * 4;   // h_k broadcast source

    const float* px   = x   + (size_t)b * (T_STEPS * 6);
    float*       pout = out + (size_t)b * (T_STEPS * 6);

    auto loadx = [&](int t, float v[6]) {
        const float2* p2 = reinterpret_cast<const float2*>(px + (size_t)t * 6);
        float2 a = p2[0], bq = p2[1], cq = p2[2];
        v[0] = a.x; v[1] = a.y; v[2] = bq.x; v[3] = bq.y; v[4] = cq.x; v[5] = cq.y;
    };
    // tree-form 6-dot with bias seed (shorter dep chain than straight chain)
    auto dotW = [&](const float w[6], const float in[6], float bias) -> float {
        float e0 = fmaf(w[0], in[0], bias);
        e0 = fmaf(w[2], in[2], e0);
        e0 = fmaf(w[4], in[4], e0);
        float e1 = w[1] * in[1];
        e1 = fmaf(w[3], in[3], e1);
        e1 = fmaf(w[5], in[5], e1);
        return e0 + e1;
    };
    auto act = [&](float g) -> float {
        return fmaf(mulc, vrcp(1.0f + vexp2(g * kscale)), addc);
    };
    auto tanhc = [&](float c) -> float {
        return fmaf(2.0f, vrcp(1.0f + vexp2(c * (-2.0f * LOG2E))), -1.0f);
    };

    float h0s[6], h1s[6];
#pragma unroll
    for (int k = 0; k < 6; ++k) { h0s[k] = 0.0f; h1s[k] = 0.0f; }
    float c0 = 0.0f, c1 = 0.0f;

    // ---- prologue: layer0 at t=0 (h=0, c=0) ----
    float xv[6];
    loadx(0, xv);
    float ga = dotW(wih0v, xv, b0);
    float a  = act(ga);
    float fS = bperm(giF, a), gS = bperm(giG, a), oS = bperm(giO, a);
    c0 = a * gS;                              // f*0 + i*g
    float h0v = oS * tanhc(c0);
#pragma unroll
    for (int k = 0; k < 6; ++k) h0s[k] = bperm(biX[k], h0v);

    float xn[6];
    loadx(1, xn);
    float xacc0 = dotW(wih0v, xn, b0);        // input-part for layer0 @ t=1
    float xacc1 = dotW(wih1v, h0s, b1);       // input-part for layer1 @ t=0
    loadx(2, xn);                             // xn = x(2)

    // ---- body: iteration t runs layer1(t-1) and layer0(t) as independent chains ----
    for (int t = 1; t < T_STEPS; ++t) {
        // layer1 gates (t-1) -> issue gather
        float g1 = dotW(whh1v, h1s, xacc1);
        float a1 = act(g1);
        float f1 = bperm(giF, a1), gg1 = bperm(giG, a1), o1 = bperm(giO, a1);
        // layer0 gates (t) -> issue gather (independent of layer1's wait)
        float g0 = dotW(whh0v, h0s, xacc0);
        float a0 = act(g0);
        float f0 = bperm(giF, a0), gg0 = bperm(giG, a0), o0 = bperm(giO, a0);
        // finish layer1: c/h update, issue h1 broadcast
        c1 = fmaf(f1, c1, a1 * gg1);
        float h1v = o1 * tanhc(c1);
#pragma unroll
        for (int k = 0; k < 6; ++k) h1s[k] = bperm(biX[k], h1v);
        // finish layer0: c/h update, issue h0 broadcast
        c0 = fmaf(f0, c0, a0 * gg0);
        h0v = o0 * tanhc(c0);
#pragma unroll
        for (int k = 0; k < 6; ++k) h0s[k] = bperm(biX[k], h0v);
        // off-critical-path work while broadcasts are in flight
        xacc0 = dotW(wih0v, xn, b0);          // uses x(t+1), loaded last iter
        int tn = t + 2; if (tn > T_STEPS - 1) tn = T_STEPS - 1;
        loadx(tn, xn);                        // prefetch x(t+2)
        if (valid && hl < 6)
            pout[(size_t)(t - 1) * 6 + hl] = h1v;
        // layer1 input-part for step t (needs h0s = h0(t), i.e. after bcast0)
        xacc1 = dotW(wih1v, h0s, b1);
    }

    // ---- epilogue: layer1 at t = T-1 ----
    {
        float g1 = dotW(whh1v, h1s, xacc1);
        float a1 = act(g1);
        float f1 = bperm(giF, a1), gg1 = bperm(giG, a1), o1 = bperm(giO, a1);
        c1 = fmaf(f1, c1, a1 * gg1);
        float h1v = o1 * tanhc(c1);
        if (valid && hl < 6)
            pout[(size_t)(T_STEPS - 1) * 6 + hl] = h1v;
    }
}

extern "C" void kernel_launch(void* const* d_in, const int* in_sizes, int n_in,
                              void* d_out, int out_size, void* d_ws, size_t ws_size,
                              hipStream_t stream)
{
    const float* x    = (const float*)d_in[0];
    const float* wih0 = (const float*)d_in[1];
    const float* whh0 = (const float*)d_in[2];
    const float* bih0 = (const float*)d_in[3];
    const float* bhh0 = (const float*)d_in[4];
    const float* wih1 = (const float*)d_in[5];
    const float* whh1 = (const float*)d_in[6];
    const float* bih1 = (const float*)d_in[7];
    const float* bhh1 = (const float*)d_in[8];
    float* out = (float*)d_out;

    const int Btot   = in_sizes[0] / (T_STEPS * 6);
    const int blocks = (Btot + 7) / 8;        // 8 elements per 256-thread block
    hipLaunchKernelGGL(lstm2_kernel, dim3(blocks), dim3(256), 0, stream,
                       x, wih0, whh0, bih0, bhh0, wih1, whh1, bih1, bhh1, out, Btot);
}